// Round 1
// baseline (76.477 us; speedup 1.0000x reference)
//
#include <hip/hip_runtime.h>

// FGN layer, ordinal=2:
//   out[b,o] = (X·W^T + bias) * exp(-( X2·S2^T - 2*X·(S2*C)^T + k[o] ))
// where S2 = inv_covars^2 + 1e-32, k[o] = sum_i S2[o,i]*C[o,i]^2.
// B=1024, I=O=512. Three fused bf16 MFMA GEMMs from a fragment-major ws layout.

typedef __bf16 bf16x8 __attribute__((ext_vector_type(8)));
typedef unsigned short u16x8 __attribute__((ext_vector_type(8)));
typedef float f32x4 __attribute__((ext_vector_type(4)));

#define B_DIM 1024
#define I_DIM 512
#define O_DIM 512

// fragment-major layout for an [R][512] array (bf16):
//   elem(r, k) stored at  rt*8192 + ks*512 + l*8 + j
//   where rt=r/16, ri=r%16, ks=k/32, chunk=(k%32)/8, j=k%8, lane l=(chunk<<4)|ri.
// A wave's MFMA fragment (rt, ks) = 1KB contiguous: lane l reads 16B at l*8 elems.

__device__ __forceinline__ unsigned short f2bf(float f) {
  unsigned u = __float_as_uint(f);
  u += 0x7fffu + ((u >> 16) & 1u);   // round-to-nearest-even
  return (unsigned short)(u >> 16);
}

// sections (groups of 8 bf16): X/X2: 65536 groups; W: 32768; C/IC: 32768  => 131072
__global__ __launch_bounds__(256) void prep_kernel(
    const float* __restrict__ xin, const float* __restrict__ win,
    const float* __restrict__ cin, const float* __restrict__ icin,
    unsigned short* __restrict__ xf, unsigned short* __restrict__ x2f,
    unsigned short* __restrict__ wf, unsigned short* __restrict__ scf,
    unsigned short* __restrict__ s2f) {
  int g = blockIdx.x * 256 + threadIdx.x;          // 0..131071
  int kind, sg;
  if (g < 65536)      { kind = 0; sg = g; }
  else if (g < 98304) { kind = 1; sg = g - 65536; }
  else                { kind = 2; sg = g - 98304; }
  int rt = sg >> 10, rem = sg & 1023, ks = rem >> 6, l = rem & 63;
  int src = ((rt << 4) + (l & 15)) * I_DIM + (ks << 5) + ((l >> 4) << 3);
  int dst = sg * 8;
  if (kind == 0) {
    f32x4 a = *reinterpret_cast<const f32x4*>(xin + src);
    f32x4 b = *reinterpret_cast<const f32x4*>(xin + src + 4);
    u16x8 o1, o2;
#pragma unroll
    for (int j = 0; j < 4; j++) {
      o1[j] = f2bf(a[j]);      o1[j + 4] = f2bf(b[j]);
      o2[j] = f2bf(a[j]*a[j]); o2[j + 4] = f2bf(b[j]*b[j]);
    }
    *reinterpret_cast<u16x8*>(xf + dst)  = o1;
    *reinterpret_cast<u16x8*>(x2f + dst) = o2;
  } else if (kind == 1) {
    f32x4 a = *reinterpret_cast<const f32x4*>(win + src);
    f32x4 b = *reinterpret_cast<const f32x4*>(win + src + 4);
    u16x8 o1;
#pragma unroll
    for (int j = 0; j < 4; j++) { o1[j] = f2bf(a[j]); o1[j + 4] = f2bf(b[j]); }
    *reinterpret_cast<u16x8*>(wf + dst) = o1;
  } else {
    f32x4 c0 = *reinterpret_cast<const f32x4*>(cin + src);
    f32x4 c1 = *reinterpret_cast<const f32x4*>(cin + src + 4);
    f32x4 q0 = *reinterpret_cast<const f32x4*>(icin + src);
    f32x4 q1 = *reinterpret_cast<const f32x4*>(icin + src + 4);
    u16x8 osc, os2;
#pragma unroll
    for (int j = 0; j < 4; j++) {
      float s2a = q0[j]*q0[j] + 1e-32f;
      float s2b = q1[j]*q1[j] + 1e-32f;
      osc[j] = f2bf(s2a * c0[j]); osc[j + 4] = f2bf(s2b * c1[j]);
      os2[j] = f2bf(s2a);         os2[j + 4] = f2bf(s2b);
    }
    *reinterpret_cast<u16x8*>(scf + dst) = osc;
    *reinterpret_cast<u16x8*>(s2f + dst) = os2;
  }
}

// k[o] = sum_i s2*c^2, one wave per o-row
__global__ __launch_bounds__(64) void prep_k_kernel(
    const float* __restrict__ cin, const float* __restrict__ icin,
    float* __restrict__ kvec) {
  int o = blockIdx.x, l = threadIdx.x;
  int base = o * I_DIM + l * 8;
  f32x4 c0 = *reinterpret_cast<const f32x4*>(cin + base);
  f32x4 c1 = *reinterpret_cast<const f32x4*>(cin + base + 4);
  f32x4 q0 = *reinterpret_cast<const f32x4*>(icin + base);
  f32x4 q1 = *reinterpret_cast<const f32x4*>(icin + base + 4);
  float s = 0.f;
#pragma unroll
  for (int j = 0; j < 4; j++) {
    float s2a = q0[j]*q0[j] + 1e-32f;
    float s2b = q1[j]*q1[j] + 1e-32f;
    s += s2a * c0[j] * c0[j] + s2b * c1[j] * c1[j];
  }
#pragma unroll
  for (int d = 32; d >= 1; d >>= 1) s += __shfl_xor(s, d, 64);
  if (l == 0) kvec[o] = s;
}

// one wave per block, 32x32 output tile; grid (32, 16)
__global__ __launch_bounds__(64) void gemm_kernel(
    const unsigned short* __restrict__ xf, const unsigned short* __restrict__ x2f,
    const unsigned short* __restrict__ wf, const unsigned short* __restrict__ scf,
    const unsigned short* __restrict__ s2f, const float* __restrict__ kvec,
    const float* __restrict__ bias, float* __restrict__ out) {
  const int l = threadIdx.x;
  const int MT = blockIdx.x;   // 0..31
  const int NT = blockIdx.y;   // 0..15
  const int lo = l * 8;

  const unsigned short* xb[2]  = { xf  + (2*MT    ) * 8192 + lo, xf  + (2*MT + 1) * 8192 + lo };
  const unsigned short* x2b[2] = { x2f + (2*MT    ) * 8192 + lo, x2f + (2*MT + 1) * 8192 + lo };
  const unsigned short* wb[2]  = { wf  + (2*NT    ) * 8192 + lo, wf  + (2*NT + 1) * 8192 + lo };
  const unsigned short* scb[2] = { scf + (2*NT    ) * 8192 + lo, scf + (2*NT + 1) * 8192 + lo };
  const unsigned short* s2b[2] = { s2f + (2*NT    ) * 8192 + lo, s2f + (2*NT + 1) * 8192 + lo };

  f32x4 accL[2][2], accA[2][2], accB[2][2];
#pragma unroll
  for (int m = 0; m < 2; m++)
#pragma unroll
    for (int n = 0; n < 2; n++) {
      accL[m][n] = (f32x4)(0.f); accA[m][n] = (f32x4)(0.f); accB[m][n] = (f32x4)(0.f);
    }

#pragma unroll
  for (int ks = 0; ks < 16; ks++) {
    const int off = ks * 512;
    bf16x8 xa[2], x2a[2], wfr[2], scfr[2], s2fr[2];
#pragma unroll
    for (int m = 0; m < 2; m++) {
      xa[m]  = *reinterpret_cast<const bf16x8*>(xb[m]  + off);
      x2a[m] = *reinterpret_cast<const bf16x8*>(x2b[m] + off);
    }
#pragma unroll
    for (int n = 0; n < 2; n++) {
      wfr[n]  = *reinterpret_cast<const bf16x8*>(wb[n]  + off);
      scfr[n] = *reinterpret_cast<const bf16x8*>(scb[n] + off);
      s2fr[n] = *reinterpret_cast<const bf16x8*>(s2b[n] + off);
    }
#pragma unroll
    for (int m = 0; m < 2; m++)
#pragma unroll
      for (int n = 0; n < 2; n++) {
        accL[m][n] = __builtin_amdgcn_mfma_f32_16x16x32_bf16(xa[m],  wfr[n],  accL[m][n], 0, 0, 0);
        accA[m][n] = __builtin_amdgcn_mfma_f32_16x16x32_bf16(xa[m],  scfr[n], accA[m][n], 0, 0, 0);
        accB[m][n] = __builtin_amdgcn_mfma_f32_16x16x32_bf16(x2a[m], s2fr[n], accB[m][n], 0, 0, 0);
      }
  }

  // C/D layout (m89-verified): col = lane&15, row = (lane>>4)*4 + reg
  const int rbase = (l >> 4) << 2;
  const int cq = l & 15;
#pragma unroll
  for (int n = 0; n < 2; n++) {
    const int ocol = NT * 32 + n * 16 + cq;
    const float bv = bias[ocol];
    const float kv = kvec[ocol];
#pragma unroll
    for (int m = 0; m < 2; m++) {
      const int orow0 = MT * 32 + m * 16 + rbase;
#pragma unroll
      for (int r = 0; r < 4; r++) {
        float g = accB[m][n][r] - 2.0f * accA[m][n][r] + kv;
        out[(orow0 + r) * O_DIM + ocol] = (accL[m][n][r] + bv) * __expf(-g);
      }
    }
  }
}

extern "C" void kernel_launch(void* const* d_in, const int* in_sizes, int n_in,
                              void* d_out, int out_size, void* d_ws, size_t ws_size,
                              hipStream_t stream) {
  const float* xin  = (const float*)d_in[0];  // inputs    [1024,512]
  const float* win  = (const float*)d_in[1];  // weights   [512,512]
  const float* bias = (const float*)d_in[2];  // biases    [512]
  const float* cin  = (const float*)d_in[3];  // centers   [512,512]
  const float* icin = (const float*)d_in[4];  // inv_covars[512,512]
  float* out = (float*)d_out;

  unsigned short* ws  = (unsigned short*)d_ws;
  unsigned short* xf  = ws;                    // 524288 bf16
  unsigned short* x2f = xf  + 524288;          // 524288
  unsigned short* wf  = x2f + 524288;          // 262144
  unsigned short* scf = wf  + 262144;          // 262144
  unsigned short* s2f = scf + 262144;          // 262144
  float* kvec = (float*)(s2f + 262144);        // 512 f32  (total ~3.67 MB)

  prep_kernel<<<512, 256, 0, stream>>>(xin, win, cin, icin, xf, x2f, wf, scf, s2f);
  prep_k_kernel<<<512, 64, 0, stream>>>(cin, icin, kvec);
  gemm_kernel<<<dim3(32, 16), 64, 0, stream>>>(xf, x2f, wf, scf, s2f, kvec, bias, out);
}

// Round 2
// 70.790 us; speedup vs baseline: 1.0803x; 1.0803x over previous
//
#include <hip/hip_runtime.h>

// FGN layer, ordinal=2:
//   out[b,o] = (X·W^T + bias) * exp(-( X2·S2^T - 2*X·(S2*C)^T + k[o] ))
// where S2 = inv_covars^2 + 1e-32, k[o] = sum_i S2[o,i]*C[o,i]^2.
// B=1024, I=O=512. Three fused bf16 MFMA GEMMs from a fragment-major ws layout.
// R2: prep_k fused into prep (2 kernels total); gemm 32x16 wave tiles (1024
// one-wave blocks = 4 waves/CU) for latency hiding + lower VGPR pressure.

typedef __bf16 bf16x8 __attribute__((ext_vector_type(8)));
typedef unsigned short u16x8 __attribute__((ext_vector_type(8)));
typedef float f32x4 __attribute__((ext_vector_type(4)));

#define B_DIM 1024
#define I_DIM 512
#define O_DIM 512

// fragment-major layout for an [R][512] array (bf16):
//   elem(r, k) stored at  rt*8192 + ks*512 + l*8 + j
//   where rt=r/16, ri=r%16, ks=k/32, chunk=(k%32)/8, j=k%8, lane l=(chunk<<4)|ri.
// A wave's MFMA fragment (rt, ks) = 1KB contiguous: lane l reads 16B at l*8 elems.

__device__ __forceinline__ unsigned short f2bf(float f) {
  unsigned u = __float_as_uint(f);
  u += 0x7fffu + ((u >> 16) & 1u);   // round-to-nearest-even
  return (unsigned short)(u >> 16);
}

// kinds (by global thread id g):
//   [0,      65536)  X/X2 fragment groups (65536 groups of 8)
//   [65536,  98304)  W
//   [98304, 131072)  C/IC -> scf/s2f
//   [131072,163840)  kvec: one wave per o-row (512 waves)
__global__ __launch_bounds__(256) void prep_kernel(
    const float* __restrict__ xin, const float* __restrict__ win,
    const float* __restrict__ cin, const float* __restrict__ icin,
    unsigned short* __restrict__ xf, unsigned short* __restrict__ x2f,
    unsigned short* __restrict__ wf, unsigned short* __restrict__ scf,
    unsigned short* __restrict__ s2f, float* __restrict__ kvec) {
  int g = blockIdx.x * 256 + threadIdx.x;
  if (g >= 131072) {
    // kvec: wave w handles o-row
    int o = (g - 131072) >> 6;
    int l = g & 63;
    int base = o * I_DIM + l * 8;
    f32x4 c0 = *reinterpret_cast<const f32x4*>(cin + base);
    f32x4 c1 = *reinterpret_cast<const f32x4*>(cin + base + 4);
    f32x4 q0 = *reinterpret_cast<const f32x4*>(icin + base);
    f32x4 q1 = *reinterpret_cast<const f32x4*>(icin + base + 4);
    float s = 0.f;
#pragma unroll
    for (int j = 0; j < 4; j++) {
      float s2a = q0[j]*q0[j] + 1e-32f;
      float s2b = q1[j]*q1[j] + 1e-32f;
      s += s2a * c0[j] * c0[j] + s2b * c1[j] * c1[j];
    }
#pragma unroll
    for (int d = 32; d >= 1; d >>= 1) s += __shfl_xor(s, d, 64);
    if (l == 0) kvec[o] = s;
    return;
  }
  int kind, sg;
  if (g < 65536)      { kind = 0; sg = g; }
  else if (g < 98304) { kind = 1; sg = g - 65536; }
  else                { kind = 2; sg = g - 98304; }
  int rt = sg >> 10, rem = sg & 1023, ks = rem >> 6, l = rem & 63;
  int src = ((rt << 4) + (l & 15)) * I_DIM + (ks << 5) + ((l >> 4) << 3);
  int dst = sg * 8;
  if (kind == 0) {
    f32x4 a = *reinterpret_cast<const f32x4*>(xin + src);
    f32x4 b = *reinterpret_cast<const f32x4*>(xin + src + 4);
    u16x8 o1, o2;
#pragma unroll
    for (int j = 0; j < 4; j++) {
      o1[j] = f2bf(a[j]);      o1[j + 4] = f2bf(b[j]);
      o2[j] = f2bf(a[j]*a[j]); o2[j + 4] = f2bf(b[j]*b[j]);
    }
    *reinterpret_cast<u16x8*>(xf + dst)  = o1;
    *reinterpret_cast<u16x8*>(x2f + dst) = o2;
  } else if (kind == 1) {
    f32x4 a = *reinterpret_cast<const f32x4*>(win + src);
    f32x4 b = *reinterpret_cast<const f32x4*>(win + src + 4);
    u16x8 o1;
#pragma unroll
    for (int j = 0; j < 4; j++) { o1[j] = f2bf(a[j]); o1[j + 4] = f2bf(b[j]); }
    *reinterpret_cast<u16x8*>(wf + dst) = o1;
  } else {
    f32x4 c0 = *reinterpret_cast<const f32x4*>(cin + src);
    f32x4 c1 = *reinterpret_cast<const f32x4*>(cin + src + 4);
    f32x4 q0 = *reinterpret_cast<const f32x4*>(icin + src);
    f32x4 q1 = *reinterpret_cast<const f32x4*>(icin + src + 4);
    u16x8 osc, os2;
#pragma unroll
    for (int j = 0; j < 4; j++) {
      float s2a = q0[j]*q0[j] + 1e-32f;
      float s2b = q1[j]*q1[j] + 1e-32f;
      osc[j] = f2bf(s2a * c0[j]); osc[j + 4] = f2bf(s2b * c1[j]);
      os2[j] = f2bf(s2a);         os2[j + 4] = f2bf(s2b);
    }
    *reinterpret_cast<u16x8*>(scf + dst) = osc;
    *reinterpret_cast<u16x8*>(s2f + dst) = os2;
  }
}

// one wave per block, 32x16 output tile; grid (MT=32, NT=32) = 1024 blocks
__global__ __launch_bounds__(64) void gemm_kernel(
    const unsigned short* __restrict__ xf, const unsigned short* __restrict__ x2f,
    const unsigned short* __restrict__ wf, const unsigned short* __restrict__ scf,
    const unsigned short* __restrict__ s2f, const float* __restrict__ kvec,
    const float* __restrict__ bias, float* __restrict__ out) {
  const int l = threadIdx.x;
  const int MT = blockIdx.x;   // 0..31  (row tile of 32)
  const int NT = blockIdx.y;   // 0..31  (col tile of 16)
  const int lo = l * 8;

  const unsigned short* xb0  = xf  + (2*MT    ) * 8192 + lo;
  const unsigned short* xb1  = xf  + (2*MT + 1) * 8192 + lo;
  const unsigned short* x2b0 = x2f + (2*MT    ) * 8192 + lo;
  const unsigned short* x2b1 = x2f + (2*MT + 1) * 8192 + lo;
  const unsigned short* wb   = wf  + NT * 8192 + lo;
  const unsigned short* scb  = scf + NT * 8192 + lo;
  const unsigned short* s2b  = s2f + NT * 8192 + lo;

  f32x4 accL[2], accA[2], accB[2];
#pragma unroll
  for (int m = 0; m < 2; m++) {
    accL[m] = (f32x4)(0.f); accA[m] = (f32x4)(0.f); accB[m] = (f32x4)(0.f);
  }

#pragma unroll
  for (int ks = 0; ks < 16; ks++) {
    const int off = ks * 512;
    bf16x8 xa0  = *reinterpret_cast<const bf16x8*>(xb0  + off);
    bf16x8 xa1  = *reinterpret_cast<const bf16x8*>(xb1  + off);
    bf16x8 x2a0 = *reinterpret_cast<const bf16x8*>(x2b0 + off);
    bf16x8 x2a1 = *reinterpret_cast<const bf16x8*>(x2b1 + off);
    bf16x8 wfr  = *reinterpret_cast<const bf16x8*>(wb   + off);
    bf16x8 scfr = *reinterpret_cast<const bf16x8*>(scb  + off);
    bf16x8 s2fr = *reinterpret_cast<const bf16x8*>(s2b  + off);
    accL[0] = __builtin_amdgcn_mfma_f32_16x16x32_bf16(xa0,  wfr,  accL[0], 0, 0, 0);
    accL[1] = __builtin_amdgcn_mfma_f32_16x16x32_bf16(xa1,  wfr,  accL[1], 0, 0, 0);
    accA[0] = __builtin_amdgcn_mfma_f32_16x16x32_bf16(xa0,  scfr, accA[0], 0, 0, 0);
    accA[1] = __builtin_amdgcn_mfma_f32_16x16x32_bf16(xa1,  scfr, accA[1], 0, 0, 0);
    accB[0] = __builtin_amdgcn_mfma_f32_16x16x32_bf16(x2a0, s2fr, accB[0], 0, 0, 0);
    accB[1] = __builtin_amdgcn_mfma_f32_16x16x32_bf16(x2a1, s2fr, accB[1], 0, 0, 0);
  }

  // C/D layout (m89-verified): col = lane&15, row = (lane>>4)*4 + reg
  const int rbase = (l >> 4) << 2;
  const int cq = l & 15;
  const int ocol = NT * 16 + cq;
  const float bv = bias[ocol];
  const float kv = kvec[ocol];
#pragma unroll
  for (int m = 0; m < 2; m++) {
    const int orow0 = MT * 32 + m * 16 + rbase;
#pragma unroll
    for (int r = 0; r < 4; r++) {
      float g = accB[m][r] - 2.0f * accA[m][r] + kv;
      out[(orow0 + r) * O_DIM + ocol] = (accL[m][r] + bv) * __expf(-g);
    }
  }
}

extern "C" void kernel_launch(void* const* d_in, const int* in_sizes, int n_in,
                              void* d_out, int out_size, void* d_ws, size_t ws_size,
                              hipStream_t stream) {
  const float* xin  = (const float*)d_in[0];  // inputs    [1024,512]
  const float* win  = (const float*)d_in[1];  // weights   [512,512]
  const float* bias = (const float*)d_in[2];  // biases    [512]
  const float* cin  = (const float*)d_in[3];  // centers   [512,512]
  const float* icin = (const float*)d_in[4];  // inv_covars[512,512]
  float* out = (float*)d_out;

  unsigned short* ws  = (unsigned short*)d_ws;
  unsigned short* xf  = ws;                    // 524288 bf16
  unsigned short* x2f = xf  + 524288;          // 524288
  unsigned short* wf  = x2f + 524288;          // 262144
  unsigned short* scf = wf  + 262144;          // 262144
  unsigned short* s2f = scf + 262144;          // 262144
  float* kvec = (float*)(s2f + 262144);        // 512 f32  (total ~3.67 MB)

  prep_kernel<<<640, 256, 0, stream>>>(xin, win, cin, icin, xf, x2f, wf, scf, s2f, kvec);
  gemm_kernel<<<dim3(32, 32), 64, 0, stream>>>(xf, x2f, wf, scf, s2f, kvec, bias, out);
}